// Round 8
// baseline (458.471 us; speedup 1.0000x reference)
//
#include <hip/hip_runtime.h>

#define N_NODES 50000
#define N_EDGES 800000
#define IN_DIM  128
#define HID_DIM 64
#define OUT_DIM 64
#define NB_NODE 196          // ceil(50000/256)
#define NSHARD 8
#define SHARD_SZ 6250        // 50000/8
#define WINDOW 2048          // edges per ticket window (256 thr x 8)
#define NWIN ((N_EDGES + WINDOW - 1) / WINDOW)   // 391
#define SCAT_BLOCKS 3136
#define GEMM1_BLOCKS 3125    // 50000/16
#define AGG_BLOCKS 3125      // 50000/16

typedef _Float16 half4v __attribute__((ext_vector_type(4)));

__device__ __forceinline__ void f4addh(float4& a, const half4v v) {
    a.x += (float)v.x; a.y += (float)v.y; a.z += (float)v.z; a.w += (float)v.w;
}

__device__ __forceinline__ int get_xcd() {
    unsigned x;
    asm volatile("s_getreg_b32 %0, hwreg(HW_REG_XCC_ID)" : "=s"(x));
    return (int)(x & 7);
}

// ---------------- init: counts + shard tickets ----------------
__global__ void k_zero(int* __restrict__ counts, int* __restrict__ ticket) {
    int i = blockIdx.x * blockDim.x + threadIdx.x;
    if (i < N_NODES) counts[i] = 0;
    if (i < NSHARD) ticket[i] = 0;
}

// simple histogram (atomics execute at coherence point regardless of locality)
__global__ void k_count(const int* __restrict__ dst, int* __restrict__ counts) {
    const int e0 = (blockIdx.x * blockDim.x + threadIdx.x) * 4;
    if (e0 + 3 < N_EDGES) {          // N_EDGES % 4 == 0
        const int4 d4 = *reinterpret_cast<const int4*>(&dst[e0]);
        atomicAdd(&counts[d4.x], 1);
        atomicAdd(&counts[d4.y], 1);
        atomicAdd(&counts[d4.z], 1);
        atomicAdd(&counts[d4.w], 1);
    }
}

__global__ void k_scan_local(const int* __restrict__ counts, int* __restrict__ ex,
                             int* __restrict__ bsum) {
    __shared__ int s[256];
    const int t = threadIdx.x;
    const int i = blockIdx.x * 256 + t;
    int v = (i < N_NODES) ? counts[i] : 0;
    s[t] = v;
    __syncthreads();
    for (int off = 1; off < 256; off <<= 1) {
        int add = (t >= off) ? s[t - off] : 0;
        __syncthreads();
        s[t] += add;
        __syncthreads();
    }
    if (i < N_NODES) ex[i] = s[t] - v;
    if (t == 255) bsum[blockIdx.x] = s[255];
}

__global__ void k_scan_bsum(int* __restrict__ bsum) {
    __shared__ int s[256];
    const int t = threadIdx.x;
    int v = (t < NB_NODE) ? bsum[t] : 0;
    s[t] = v;
    __syncthreads();
    for (int off = 1; off < 256; off <<= 1) {
        int add = (t >= off) ? s[t - off] : 0;
        __syncthreads();
        s[t] += add;
        __syncthreads();
    }
    if (t < NB_NODE) bsum[t] = s[t] - v;  // exclusive
}

__global__ void k_finalize(const int* __restrict__ counts, const int* __restrict__ ex,
                           const int* __restrict__ bsum, int* __restrict__ offsets,
                           int* __restrict__ cursor, float* __restrict__ dinv) {
    int i = blockIdx.x * blockDim.x + threadIdx.x;
    if (i >= N_NODES) return;
    int o = ex[i] + bsum[blockIdx.x];
    offsets[i] = o;
    cursor[i] = o;
    dinv[i] = rsqrtf((float)(counts[i] + 1));  // +1: self-loop
}

// ---------------- fused: XCD-sharded scatter (blocks < SCAT_BLOCKS) || gemm1 --------
// Scatter: each block prefers the dst-range matching its physical XCD (csr lines stay
// in the local L2), pulls 2048-edge windows off a per-shard ticket; after its shard is
// drained it steals other shards' windows -> coverage never depends on placement.
__global__ __launch_bounds__(256) void k_scatter_gemm1(
        const int* __restrict__ src, const int* __restrict__ dst,
        int* __restrict__ cursor, int* __restrict__ ticket,
        unsigned short* __restrict__ csr,
        const float* __restrict__ x, const float* __restrict__ W1,
        const float* __restrict__ dinv, _Float16* __restrict__ h1s) {
    __shared__ float xs[16][IN_DIM];   // gemm1 role only (8 KB)
    __shared__ int wsh;
    const int bid = blockIdx.x;
    if (bid < SCAT_BLOCKS) {
        const int myx = get_xcd();
        for (int t = 0; t < NSHARD; ++t) {
            const int shard = (myx + t) & 7;
            const int lo = shard * SHARD_SZ, hi = lo + SHARD_SZ;
            while (true) {
                if (threadIdx.x == 0) wsh = atomicAdd(&ticket[shard], 1);
                __syncthreads();
                const int w = wsh;
                __syncthreads();
                if (w >= NWIN) break;
                const int base = w * WINDOW;
#pragma unroll
                for (int k = 0; k < 8; ++k) {
                    const int e = base + k * 256 + threadIdx.x;
                    if (e < N_EDGES) {
                        const int d = dst[e];
                        if (d >= lo && d < hi)
                            csr[atomicAdd(&cursor[d], 1)] = (unsigned short)src[e];
                    }
                }
            }
        }
        return;
    }
    // ---- gemm1 role: 16 nodes/block, 4 nodes/thread (round-6 body) ----
    const int t = threadIdx.x;
    const int wave = t >> 6;
    const int lane = t & 63;
    const long base = (long)(bid - SCAT_BLOCKS) * 16;
    {
        float4* xsv = reinterpret_cast<float4*>(&xs[0][0]);
        const float4* xv = reinterpret_cast<const float4*>(&x[base * IN_DIM]);
        xsv[t]       = xv[t];
        xsv[t + 256] = xv[t + 256];
    }
    __syncthreads();
    const int n0 = wave * 4, n1 = n0 + 1, n2 = n0 + 2, n3 = n0 + 3;
    float a0 = 0.f, a1 = 0.f, a2 = 0.f, a3 = 0.f;
#pragma unroll 8
    for (int k = 0; k < IN_DIM; ++k) {
        const float wv = W1[k * HID_DIM + lane];
        a0 = fmaf(xs[n0][k], wv, a0);
        a1 = fmaf(xs[n1][k], wv, a1);
        a2 = fmaf(xs[n2][k], wv, a2);
        a3 = fmaf(xs[n3][k], wv, a3);
    }
    h1s[(base + n0) * HID_DIM + lane] = (_Float16)(a0 * dinv[base + n0]);
    h1s[(base + n1) * HID_DIM + lane] = (_Float16)(a1 * dinv[base + n1]);
    h1s[(base + n2) * HID_DIM + lane] = (_Float16)(a2 * dinv[base + n2]);
    h1s[(base + n3) * HID_DIM + lane] = (_Float16)(a3 * dinv[base + n3]);
}

// ---------------- gather core: one 16-lane group owns one node, 8-deep pipeline ------
__device__ __forceinline__ float4 gather_node(
        const unsigned short* __restrict__ csr, const _Float16* __restrict__ h,
        int n, int beg, int cnt, int sub) {
    float4 a0 = {0,0,0,0}, a1 = {0,0,0,0}, a2 = {0,0,0,0}, a3 = {0,0,0,0};
    int e = 0;
    for (; e + 8 <= cnt; e += 8) {
        int idx[8];
#pragma unroll
        for (int j = 0; j < 8; ++j) idx[j] = csr[beg + e + j];
        half4v v[8];
#pragma unroll
        for (int j = 0; j < 8; ++j)
            v[j] = *reinterpret_cast<const half4v*>(&h[(long)idx[j] * 64 + sub * 4]);
        f4addh(a0, v[0]); f4addh(a1, v[1]); f4addh(a2, v[2]); f4addh(a3, v[3]);
        f4addh(a0, v[4]); f4addh(a1, v[5]); f4addh(a2, v[6]); f4addh(a3, v[7]);
    }
    if (e + 4 <= cnt) {
        int idx[4];
#pragma unroll
        for (int j = 0; j < 4; ++j) idx[j] = csr[beg + e + j];
        half4v v[4];
#pragma unroll
        for (int j = 0; j < 4; ++j)
            v[j] = *reinterpret_cast<const half4v*>(&h[(long)idx[j] * 64 + sub * 4]);
        f4addh(a0, v[0]); f4addh(a1, v[1]); f4addh(a2, v[2]); f4addh(a3, v[3]);
        e += 4;
    }
    for (; e < cnt; ++e)
        f4addh(a0, *reinterpret_cast<const half4v*>(&h[(long)csr[beg + e] * 64 + sub * 4]));
    f4addh(a1, *reinterpret_cast<const half4v*>(&h[(long)n * 64 + sub * 4]));  // self-loop
    float4 a;
    a.x = (a0.x + a1.x) + (a2.x + a3.x);
    a.y = (a0.y + a1.y) + (a2.y + a3.y);
    a.z = (a0.z + a1.z) + (a2.z + a3.z);
    a.w = (a0.w + a1.w) + (a2.w + a3.w);
    return a;
}

// ---------------- fused: agg layer1 + bias + ReLU + GEMM2 + pre-scale ---------------
__global__ __launch_bounds__(256) void k_agg1_fused(
        const unsigned short* __restrict__ csr, const int* __restrict__ offsets,
        const int* __restrict__ counts, const float* __restrict__ dinv,
        const _Float16* __restrict__ h1s, const float* __restrict__ b1,
        const float* __restrict__ W2, _Float16* __restrict__ h3s) {
    __shared__ float rs[16][HID_DIM];   // 4 KB
    const int g = threadIdx.x >> 4;
    const int sub = threadIdx.x & 15;
    const long nbase = (long)blockIdx.x * 16;
    const int n = (int)nbase + g;
    const int beg = offsets[n];
    const int cnt = counts[n];
    float4 a = gather_node(csr, h1s, n, beg, cnt, sub);
    const float di = dinv[n];
    const float4 bv = *reinterpret_cast<const float4*>(&b1[sub * 4]);
    float4 r;
    r.x = fmaxf(a.x * di + bv.x, 0.0f);
    r.y = fmaxf(a.y * di + bv.y, 0.0f);
    r.z = fmaxf(a.z * di + bv.z, 0.0f);
    r.w = fmaxf(a.w * di + bv.w, 0.0f);
    *reinterpret_cast<float4*>(&rs[g][sub * 4]) = r;
    __syncthreads();
    // GEMM phase: wave w computes nodes 4w..4w+3
    const int wave = threadIdx.x >> 6;
    const int lane = threadIdx.x & 63;
    float acc[4] = {0.f, 0.f, 0.f, 0.f};
#pragma unroll 4
    for (int k = 0; k < HID_DIM; ++k) {
        const float wv = W2[k * OUT_DIM + lane];
#pragma unroll
        for (int m = 0; m < 4; ++m)
            acc[m] = fmaf(rs[wave * 4 + m][k], wv, acc[m]);
    }
#pragma unroll
    for (int m = 0; m < 4; ++m) {
        const long node = nbase + wave * 4 + m;
        h3s[node * 64 + lane] = (_Float16)(acc[m] * dinv[node]);
    }
}

// ---------------- final aggregation ----------------
__global__ __launch_bounds__(256) void k_agg2(
        const unsigned short* __restrict__ csr, const int* __restrict__ offsets,
        const int* __restrict__ counts, const float* __restrict__ dinv,
        const _Float16* __restrict__ h3s, const float* __restrict__ b2,
        float* __restrict__ dout) {
    const int g = threadIdx.x >> 4;
    const int sub = threadIdx.x & 15;
    const int n = blockIdx.x * 16 + g;
    const int beg = offsets[n];
    const int cnt = counts[n];
    float4 a = gather_node(csr, h3s, n, beg, cnt, sub);
    const float di = dinv[n];
    const float4 bv = *reinterpret_cast<const float4*>(&b2[sub * 4]);
    float4 r;
    r.x = a.x * di + bv.x;
    r.y = a.y * di + bv.y;
    r.z = a.z * di + bv.z;
    r.w = a.w * di + bv.w;
    *reinterpret_cast<float4*>(&dout[(long)n * 64 + sub * 4]) = r;
}

extern "C" void kernel_launch(void* const* d_in, const int* in_sizes, int n_in,
                              void* d_out, int out_size, void* d_ws, size_t ws_size,
                              hipStream_t stream) {
    const float* x  = (const float*)d_in[0];
    const int*   ei = (const int*)d_in[1];          // [2, N_EDGES]
    const float* W1 = (const float*)d_in[2];
    const float* b1 = (const float*)d_in[3];
    const float* W2 = (const float*)d_in[4];
    const float* b2 = (const float*)d_in[5];
    float* dout = (float*)d_out;

    const int* src = ei;
    const int* dst = ei + N_EDGES;

    char* w = (char*)d_ws;
    int*            counts  = (int*)w;            w += 50176 * 4;
    int*            ex      = (int*)w;            w += 50176 * 4;
    int*            bsum    = (int*)w;            w += 256 * 4;
    int*            offsets = (int*)w;            w += 50176 * 4;
    int*            cursor  = (int*)w;            w += 50176 * 4;
    int*            ticket  = (int*)w;            w += 64 * 4;
    float*          dinv    = (float*)w;          w += 50176 * 4;
    unsigned short* csr     = (unsigned short*)w; w += (long)N_EDGES * 2;
    _Float16*       h1s     = (_Float16*)w;       w += (long)N_NODES * 64 * 2;
    _Float16*       h3s     = (_Float16*)w;

    k_zero<<<NB_NODE, 256, 0, stream>>>(counts, ticket);
    k_count<<<782, 256, 0, stream>>>(dst, counts);
    k_scan_local<<<NB_NODE, 256, 0, stream>>>(counts, ex, bsum);
    k_scan_bsum<<<1, 256, 0, stream>>>(bsum);
    k_finalize<<<NB_NODE, 256, 0, stream>>>(counts, ex, bsum, offsets, cursor, dinv);

    k_scatter_gemm1<<<SCAT_BLOCKS + GEMM1_BLOCKS, 256, 0, stream>>>(
        src, dst, cursor, ticket, csr, x, W1, dinv, h1s);

    k_agg1_fused<<<AGG_BLOCKS, 256, 0, stream>>>(csr, offsets, counts, dinv, h1s, b1, W2, h3s);
    k_agg2<<<AGG_BLOCKS, 256, 0, stream>>>(csr, offsets, counts, dinv, h3s, b2, dout);
}

// Round 10
// 151.418 us; speedup vs baseline: 3.0278x; 3.0278x over previous
//
#include <hip/hip_runtime.h>

#define N_NODES 50000
#define N_EDGES 800000
#define IN_DIM  128
#define HID_DIM 64
#define OUT_DIM 64
#define NB_NODE 196          // ceil(50000/256)
#define NSHARD 8
#define SHARD_SZ 6250        // 50000/8
#define SCAT_CHUNK 392
#define SCAT_BLOCKS (NSHARD * SCAT_CHUNK)   // 3136
#define GEMM1_BLOCKS 3125    // 50000/16
#define AGG_BLOCKS 3125      // 50000/16

typedef _Float16 half4v __attribute__((ext_vector_type(4)));
typedef float float4v __attribute__((ext_vector_type(4)));

__device__ __forceinline__ void f4addh(float4& a, const half4v v) {
    a.x += (float)v.x; a.y += (float)v.y; a.z += (float)v.z; a.w += (float)v.w;
}

// ---------------- CSR build ----------------
__global__ void k_zero_counts(int* __restrict__ counts) {
    int i = blockIdx.x * blockDim.x + threadIdx.x;
    if (i < N_NODES) counts[i] = 0;
}

// single-pass histogram, int4 loads (4 independent atomics in flight per thread)
__global__ void k_count(const int* __restrict__ dst, int* __restrict__ counts) {
    const int e0 = (blockIdx.x * blockDim.x + threadIdx.x) * 4;
    if (e0 + 3 < N_EDGES) {          // N_EDGES % 4 == 0
        const int4 d4 = *reinterpret_cast<const int4*>(&dst[e0]);
        atomicAdd(&counts[d4.x], 1);
        atomicAdd(&counts[d4.y], 1);
        atomicAdd(&counts[d4.z], 1);
        atomicAdd(&counts[d4.w], 1);
    }
}

__global__ void k_scan_local(const int* __restrict__ counts, int* __restrict__ ex,
                             int* __restrict__ bsum) {
    __shared__ int s[256];
    const int t = threadIdx.x;
    const int i = blockIdx.x * 256 + t;
    int v = (i < N_NODES) ? counts[i] : 0;
    s[t] = v;
    __syncthreads();
    for (int off = 1; off < 256; off <<= 1) {
        int add = (t >= off) ? s[t - off] : 0;
        __syncthreads();
        s[t] += add;
        __syncthreads();
    }
    if (i < N_NODES) ex[i] = s[t] - v;
    if (t == 255) bsum[blockIdx.x] = s[255];
}

__global__ void k_scan_bsum(int* __restrict__ bsum) {
    __shared__ int s[256];
    const int t = threadIdx.x;
    int v = (t < NB_NODE) ? bsum[t] : 0;
    s[t] = v;
    __syncthreads();
    for (int off = 1; off < 256; off <<= 1) {
        int add = (t >= off) ? s[t - off] : 0;
        __syncthreads();
        s[t] += add;
        __syncthreads();
    }
    if (t < NB_NODE) bsum[t] = s[t] - v;  // exclusive
}

__global__ void k_finalize(const int* __restrict__ counts, const int* __restrict__ ex,
                           const int* __restrict__ bsum, int* __restrict__ offsets,
                           int* __restrict__ cursor, float* __restrict__ dinv) {
    int i = blockIdx.x * blockDim.x + threadIdx.x;
    if (i >= N_NODES) return;
    int o = ex[i] + bsum[blockIdx.x];
    offsets[i] = o;
    cursor[i] = o;
    dinv[i] = rsqrtf((float)(counts[i] + 1));  // +1: self-loop
}

// ---------------- fused: sharded scatter (blocks < SCAT_BLOCKS) || gemm1 ------------
__global__ __launch_bounds__(256) void k_scatter_gemm1(
        const int* __restrict__ src, const int* __restrict__ dst,
        int* __restrict__ cursor, unsigned short* __restrict__ csr,
        const float* __restrict__ x, const float* __restrict__ W1,
        const float* __restrict__ dinv, _Float16* __restrict__ h1s) {
    __shared__ float xs[16][IN_DIM];   // 8 KB (gemm1 role only)
    const int bid = blockIdx.x;
    if (bid < SCAT_BLOCKS) {
        // ---- scatter role: shard by dst range (bid&7 ~ XCD heuristic) ----
        const int shard = bid & 7;
        const int chunk = bid >> 3;
        const int lo = shard * SHARD_SZ, hi = lo + SHARD_SZ;
        for (int base = chunk * 256; base < N_EDGES; base += SCAT_CHUNK * 256) {
            const int e = base + threadIdx.x;
            if (e < N_EDGES) {
                const int d = dst[e];
                if (d >= lo && d < hi) {
                    const int pos = atomicAdd(&cursor[d], 1);
                    csr[pos] = (unsigned short)src[e];
                }
            }
        }
        return;
    }
    // ---- gemm1 role: 16 nodes/block, 4 nodes/thread ----
    const int t = threadIdx.x;
    const int wave = t >> 6;
    const int lane = t & 63;
    const long base = (long)(bid - SCAT_BLOCKS) * 16;
    {
        float4* xsv = reinterpret_cast<float4*>(&xs[0][0]);
        const float4* xv = reinterpret_cast<const float4*>(&x[base * IN_DIM]);
        xsv[t]       = xv[t];
        xsv[t + 256] = xv[t + 256];
    }
    __syncthreads();
    const int n0 = wave * 4, n1 = n0 + 1, n2 = n0 + 2, n3 = n0 + 3;
    float a0 = 0.f, a1 = 0.f, a2 = 0.f, a3 = 0.f;
#pragma unroll 8
    for (int k = 0; k < IN_DIM; ++k) {
        const float wv = W1[k * HID_DIM + lane];
        a0 = fmaf(xs[n0][k], wv, a0);
        a1 = fmaf(xs[n1][k], wv, a1);
        a2 = fmaf(xs[n2][k], wv, a2);
        a3 = fmaf(xs[n3][k], wv, a3);
    }
    h1s[(base + n0) * HID_DIM + lane] = (_Float16)(a0 * dinv[base + n0]);
    h1s[(base + n1) * HID_DIM + lane] = (_Float16)(a1 * dinv[base + n1]);
    h1s[(base + n2) * HID_DIM + lane] = (_Float16)(a2 * dinv[base + n2]);
    h1s[(base + n3) * HID_DIM + lane] = (_Float16)(a3 * dinv[base + n3]);
}

// ---------------- gather core: one 16-lane group owns one node, 8-deep pipeline ------
__device__ __forceinline__ float4 gather_node(
        const unsigned short* __restrict__ csr, const _Float16* __restrict__ h,
        int n, int beg, int cnt, int sub) {
    float4 a0 = {0,0,0,0}, a1 = {0,0,0,0}, a2 = {0,0,0,0}, a3 = {0,0,0,0};
    int e = 0;
    for (; e + 8 <= cnt; e += 8) {
        int idx[8];
#pragma unroll
        for (int j = 0; j < 8; ++j) idx[j] = csr[beg + e + j];
        half4v v[8];
#pragma unroll
        for (int j = 0; j < 8; ++j)
            v[j] = *reinterpret_cast<const half4v*>(&h[(long)idx[j] * 64 + sub * 4]);
        f4addh(a0, v[0]); f4addh(a1, v[1]); f4addh(a2, v[2]); f4addh(a3, v[3]);
        f4addh(a0, v[4]); f4addh(a1, v[5]); f4addh(a2, v[6]); f4addh(a3, v[7]);
    }
    if (e + 4 <= cnt) {
        int idx[4];
#pragma unroll
        for (int j = 0; j < 4; ++j) idx[j] = csr[beg + e + j];
        half4v v[4];
#pragma unroll
        for (int j = 0; j < 4; ++j)
            v[j] = *reinterpret_cast<const half4v*>(&h[(long)idx[j] * 64 + sub * 4]);
        f4addh(a0, v[0]); f4addh(a1, v[1]); f4addh(a2, v[2]); f4addh(a3, v[3]);
        e += 4;
    }
    for (; e < cnt; ++e)
        f4addh(a0, *reinterpret_cast<const half4v*>(&h[(long)csr[beg + e] * 64 + sub * 4]));
    f4addh(a1, *reinterpret_cast<const half4v*>(&h[(long)n * 64 + sub * 4]));  // self-loop
    float4 a;
    a.x = (a0.x + a1.x) + (a2.x + a3.x);
    a.y = (a0.y + a1.y) + (a2.y + a3.y);
    a.z = (a0.z + a1.z) + (a2.z + a3.z);
    a.w = (a0.w + a1.w) + (a2.w + a3.w);
    return a;
}

// ---------------- fused: agg layer1 + bias + ReLU + GEMM2 + pre-scale ---------------
__global__ __launch_bounds__(256) void k_agg1_fused(
        const unsigned short* __restrict__ csr, const int* __restrict__ offsets,
        const int* __restrict__ counts, const float* __restrict__ dinv,
        const _Float16* __restrict__ h1s, const float* __restrict__ b1,
        const float* __restrict__ W2, _Float16* __restrict__ h3s) {
    __shared__ float rs[16][HID_DIM];   // 4 KB
    const int g = threadIdx.x >> 4;
    const int sub = threadIdx.x & 15;
    const long nbase = (long)blockIdx.x * 16;
    const int n = (int)nbase + g;
    const int beg = offsets[n];
    const int cnt = counts[n];
    float4 a = gather_node(csr, h1s, n, beg, cnt, sub);
    const float di = dinv[n];
    const float4 bv = *reinterpret_cast<const float4*>(&b1[sub * 4]);
    float4 r;
    r.x = fmaxf(a.x * di + bv.x, 0.0f);
    r.y = fmaxf(a.y * di + bv.y, 0.0f);
    r.z = fmaxf(a.z * di + bv.z, 0.0f);
    r.w = fmaxf(a.w * di + bv.w, 0.0f);
    *reinterpret_cast<float4*>(&rs[g][sub * 4]) = r;
    __syncthreads();
    // GEMM phase: wave w computes nodes 4w..4w+3
    const int wave = threadIdx.x >> 6;
    const int lane = threadIdx.x & 63;
    float acc[4] = {0.f, 0.f, 0.f, 0.f};
#pragma unroll 4
    for (int k = 0; k < HID_DIM; ++k) {
        const float wv = W2[k * OUT_DIM + lane];
#pragma unroll
        for (int m = 0; m < 4; ++m)
            acc[m] = fmaf(rs[wave * 4 + m][k], wv, acc[m]);
    }
#pragma unroll
    for (int m = 0; m < 4; ++m) {
        const long node = nbase + wave * 4 + m;
        h3s[node * 64 + lane] = (_Float16)(acc[m] * dinv[node]);
    }
}

// ---------------- final aggregation (non-temporal dout stores) ----------------------
__global__ __launch_bounds__(256) void k_agg2(
        const unsigned short* __restrict__ csr, const int* __restrict__ offsets,
        const int* __restrict__ counts, const float* __restrict__ dinv,
        const _Float16* __restrict__ h3s, const float* __restrict__ b2,
        float* __restrict__ dout) {
    const int g = threadIdx.x >> 4;
    const int sub = threadIdx.x & 15;
    const int n = blockIdx.x * 16 + g;
    const int beg = offsets[n];
    const int cnt = counts[n];
    float4 a = gather_node(csr, h3s, n, beg, cnt, sub);
    const float di = dinv[n];
    const float4 bv = *reinterpret_cast<const float4*>(&b2[sub * 4]);
    float4v r;
    r.x = a.x * di + bv.x;
    r.y = a.y * di + bv.y;
    r.z = a.z * di + bv.z;
    r.w = a.w * di + bv.w;
    // dout is never re-read: bypass caches to protect the h3s gather working set
    __builtin_nontemporal_store(r, reinterpret_cast<float4v*>(&dout[(long)n * 64 + sub * 4]));
}

extern "C" void kernel_launch(void* const* d_in, const int* in_sizes, int n_in,
                              void* d_out, int out_size, void* d_ws, size_t ws_size,
                              hipStream_t stream) {
    const float* x  = (const float*)d_in[0];
    const int*   ei = (const int*)d_in[1];          // [2, N_EDGES]
    const float* W1 = (const float*)d_in[2];
    const float* b1 = (const float*)d_in[3];
    const float* W2 = (const float*)d_in[4];
    const float* b2 = (const float*)d_in[5];
    float* dout = (float*)d_out;

    const int* src = ei;
    const int* dst = ei + N_EDGES;

    char* w = (char*)d_ws;
    int*            counts  = (int*)w;            w += 50176 * 4;
    int*            ex      = (int*)w;            w += 50176 * 4;
    int*            bsum    = (int*)w;            w += 256 * 4;
    int*            offsets = (int*)w;            w += 50176 * 4;
    int*            cursor  = (int*)w;            w += 50176 * 4;
    float*          dinv    = (float*)w;          w += 50176 * 4;
    unsigned short* csr     = (unsigned short*)w; w += (long)N_EDGES * 2;
    _Float16*       h1s     = (_Float16*)w;       w += (long)N_NODES * 64 * 2;
    _Float16*       h3s     = (_Float16*)w;

    k_zero_counts<<<NB_NODE, 256, 0, stream>>>(counts);
    k_count<<<782, 256, 0, stream>>>(dst, counts);
    k_scan_local<<<NB_NODE, 256, 0, stream>>>(counts, ex, bsum);
    k_scan_bsum<<<1, 256, 0, stream>>>(bsum);
    k_finalize<<<NB_NODE, 256, 0, stream>>>(counts, ex, bsum, offsets, cursor, dinv);

    k_scatter_gemm1<<<SCAT_BLOCKS + GEMM1_BLOCKS, 256, 0, stream>>>(
        src, dst, cursor, csr, x, W1, dinv, h1s);

    k_agg1_fused<<<AGG_BLOCKS, 256, 0, stream>>>(csr, offsets, counts, dinv, h1s, b1, W2, h3s);
    k_agg2<<<AGG_BLOCKS, 256, 0, stream>>>(csr, offsets, counts, dinv, h3s, b2, dout);
}